// Round 1
// baseline (8797.503 us; speedup 1.0000x reference)
//
#include <hip/hip_runtime.h>

// Problem constants
#define B_ 256
#define T_ 512
#define F_ 256
#define H_ 512
#define E_ 128

typedef __bf16 bf16x8 __attribute__((ext_vector_type(8)));
typedef float f32x4 __attribute__((ext_vector_type(4)));

__device__ __forceinline__ unsigned short f2bf(float f) {
    unsigned u = __float_as_uint(f);
    u += 0x7FFFu + ((u >> 16) & 1u);   // round-to-nearest-even
    return (unsigned short)(u >> 16);
}
__device__ __forceinline__ float bf2f(unsigned short s) {
    return __uint_as_float(((unsigned)s) << 16);
}
__device__ __forceinline__ float sigm(float x) {
    return 1.f / (1.f + __expf(-x));
}
__device__ __forceinline__ float tanh_f(float x) {
    return 2.f / (1.f + __expf(-2.f * x)) - 1.f;
}

// ---------------- prep kernels ----------------

// x fp32 -> bf16, 4 elements/thread
__global__ void cvt_x(const float* __restrict__ x, unsigned short* __restrict__ xb) {
    int i = blockIdx.x * 256 + threadIdx.x;       // 8,388,608 threads exactly
    float4 v = ((const float4*)x)[i];
    ushort4 o;
    o.x = f2bf(v.x); o.y = f2bf(v.y); o.z = f2bf(v.z); o.w = f2bf(v.w);
    ((ushort4*)xb)[i] = o;
}

// Build permuted combined weight matrix Wp[2048][768] (bf16) and bias bp[2048].
// New row nr = idx*32 + q*8 + jj  maps to old gate row  orow = q*512 + idx*8 + jj.
// k in [0,256) from W_ih, k in [256,768) from W_hh.
__global__ void prep_w(const float* __restrict__ Wih, const float* __restrict__ Whh,
                       const float* __restrict__ bih, const float* __restrict__ bhh,
                       unsigned short* __restrict__ Wp, float* __restrict__ bp) {
    int gid = blockIdx.x * 256 + threadIdx.x;     // 1,572,864 threads exactly
    int nr = gid / 768;
    int k  = gid - nr * 768;
    int idx = nr >> 5;
    int rem = nr & 31;
    int q  = rem >> 3;
    int jj = rem & 7;
    int orow = q * 512 + idx * 8 + jj;
    float v = (k < 256) ? Wih[orow * 256 + k] : Whh[orow * 512 + (k - 256)];
    Wp[gid] = f2bf(v);
    if (k == 0) bp[nr] = bih[orow] + bhh[orow];
}

// h0 fp32 -> bf16 into parity-0 h buffer; zero the barrier counters
__global__ void init_hb(const float* __restrict__ h0, unsigned short* __restrict__ hbuf,
                        int* __restrict__ bar) {
    int i = blockIdx.x * 256 + threadIdx.x;       // 131,072 threads exactly
    hbuf[i] = f2bf(h0[i]);
    if (blockIdx.x == 0 && threadIdx.x < 4) bar[threadIdx.x] = 0;
}

// ---------------- persistent LSTM kernel (cooperative) ----------------
// grid = 256 blocks x 256 threads. Block bid: cluster = bid>>6 (64 batch rows),
// idx = bid&63 (8 h-cols -> 32 permuted gate rows, LDS-resident weights).
__global__ void __launch_bounds__(256, 1) lstm_kernel(
        const unsigned short* __restrict__ xb,   // [B][T][F] bf16
        const unsigned short* __restrict__ Wp,   // [2048][768] bf16 (permuted)
        const float* __restrict__ bp,            // [2048] (permuted)
        const float* __restrict__ c0,            // [B][H] fp32
        unsigned short* __restrict__ hbuf,       // [2][B][H] bf16
        int* __restrict__ bar) {                 // [4] monotonic barrier counters

    __shared__ __align__(16) unsigned short Wl[32][776];  // 768 + 8 pad (bank spread)
    __shared__ float gl[64][33];                          // gate staging, +1 pad
    __shared__ float cl[64][8];                           // resident cell state

    const int tid = threadIdx.x;
    const int bid = blockIdx.x;
    const int cluster = bid >> 6;
    const int idx = bid & 63;
    const int m0 = cluster * 64;     // first batch row of cluster
    const int j0 = idx * 8;          // first h-col owned by this block
    const int gr0 = idx * 32;        // first permuted gate row

    // Stage weight slab (32 x 768 bf16) into LDS, once.
    {
        const ushort4* src = (const ushort4*)(Wp + (size_t)gr0 * 768);
        for (int v = tid; v < 32 * 192; v += 256) {
            int r = v / 192;
            int c = v - r * 192;
            *(ushort4*)&Wl[r][c * 4] = src[v];
        }
    }
    // Resident cell state init
    for (int p = tid; p < 512; p += 256) {
        int m = p >> 3, j = p & 7;
        cl[m][j] = c0[(size_t)(m0 + m) * H_ + j0 + j];
    }
    __syncthreads();

    const int lane = tid & 63;
    const int wave = tid >> 6;
    const int l16  = lane & 15;
    const int quad = lane >> 4;
    const int am   = m0 + wave * 16 + l16;   // this lane's A-row (global batch row)

    const float b0 = bp[gr0 + l16];          // bias for n-tile 0 (i,f)
    const float b1 = bp[gr0 + 16 + l16];     // bias for n-tile 1 (g,o)

    for (int t = 0; t < T_; ++t) {
        const int par = t & 1;
        const unsigned short* hsrc = hbuf + (size_t)par * (B_ * H_);
        unsigned short* hdst = hbuf + (size_t)(par ^ 1) * (B_ * H_);

        f32x4 acc0 = {b0, b0, b0, b0};
        f32x4 acc1 = {b1, b1, b1, b1};

        // ---- x-part (K = 0..256): independent of h -> runs before barrier wait
        {
            const unsigned short* xr =
                xb + (size_t)am * (T_ * F_) + (size_t)t * F_ + quad * 8;
            #pragma unroll
            for (int kk = 0; kk < 256; kk += 32) {
                bf16x8 a  = *(const bf16x8*)(xr + kk);
                bf16x8 w0 = *(const bf16x8*)&Wl[l16][kk + quad * 8];
                bf16x8 w1 = *(const bf16x8*)&Wl[16 + l16][kk + quad * 8];
                acc0 = __builtin_amdgcn_mfma_f32_16x16x32_bf16(a, w0, acc0, 0, 0, 0);
                acc1 = __builtin_amdgcn_mfma_f32_16x16x32_bf16(a, w1, acc1, 0, 0, 0);
            }
        }

        // ---- wait: h_t must be fully published (cnt >= 64*t)
        if (t > 0) {
            if (tid == 0) {
                const int target = t * 64;
                while (__hip_atomic_load(&bar[cluster], __ATOMIC_RELAXED,
                                         __HIP_MEMORY_SCOPE_AGENT) < target) { }
                __threadfence();   // acquire: invalidate stale L1/L2 before h reads
            }
            __syncthreads();
        }

        // ---- h-part (K = 256..768)
        {
            const unsigned short* hr = hsrc + (size_t)am * H_ + quad * 8;
            #pragma unroll
            for (int kk = 0; kk < 512; kk += 32) {
                bf16x8 a  = *(const bf16x8*)(hr + kk);
                bf16x8 w0 = *(const bf16x8*)&Wl[l16][256 + kk + quad * 8];
                bf16x8 w1 = *(const bf16x8*)&Wl[16 + l16][256 + kk + quad * 8];
                acc0 = __builtin_amdgcn_mfma_f32_16x16x32_bf16(a, w0, acc0, 0, 0, 0);
                acc1 = __builtin_amdgcn_mfma_f32_16x16x32_bf16(a, w1, acc1, 0, 0, 0);
            }
        }

        // ---- epilogue: C-layout (col=lane&15, row=quad*4+reg) -> LDS
        #pragma unroll
        for (int r = 0; r < 4; ++r) {
            gl[wave * 16 + quad * 4 + r][l16]      = acc0[r];
            gl[wave * 16 + quad * 4 + r][16 + l16] = acc1[r];
        }
        __syncthreads();

        // elementwise gate math; local n layout is [i(8) f(8) g(8) o(8)]
        #pragma unroll
        for (int p = tid; p < 512; p += 256) {
            int m = p >> 3, j = p & 7;
            float iv = sigm(gl[m][j]);
            float fv = sigm(gl[m][j + 8]);
            float gv = tanh_f(gl[m][j + 16]);
            float ov = sigm(gl[m][j + 24]);
            float c = fv * cl[m][j] + iv * gv;
            cl[m][j] = c;
            float h = ov * tanh_f(c);
            hdst[(size_t)(m0 + m) * H_ + j0 + j] = f2bf(h);
        }
        __syncthreads();                       // drains vmcnt: h stores are in L2
        if (tid == 0) {
            __threadfence();                   // release: write back L2 -> device-visible
            atomicAdd(&bar[cluster], 1);       // device-scope arrive
        }
    }
}

// ---------------- FC head ----------------
// out[m][e] = sigmoid(h_T[m] . W_fc[e] + b_fc[e]); grid = 256 (m), 128 threads (e)
__global__ void fc_kernel(const unsigned short* __restrict__ hT,
                          const float* __restrict__ Wfc,
                          const float* __restrict__ bfc,
                          float* __restrict__ out) {
    __shared__ float hs[512];
    int m = blockIdx.x;
    for (int k = threadIdx.x; k < 512; k += 128)
        hs[k] = bf2f(hT[(size_t)m * 512 + k]);
    __syncthreads();
    int e = threadIdx.x;
    const float4* w4 = (const float4*)(Wfc + (size_t)e * 512);
    float s = bfc[e];
    #pragma unroll 8
    for (int k4 = 0; k4 < 128; ++k4) {
        float4 w = w4[k4];
        s += hs[4 * k4] * w.x + hs[4 * k4 + 1] * w.y +
             hs[4 * k4 + 2] * w.z + hs[4 * k4 + 3] * w.w;
    }
    out[(size_t)m * 128 + e] = 1.f / (1.f + __expf(-s));
}

// ---------------- launch ----------------
extern "C" void kernel_launch(void* const* d_in, const int* in_sizes, int n_in,
                              void* d_out, int out_size, void* d_ws, size_t ws_size,
                              hipStream_t stream) {
    const float* x   = (const float*)d_in[0];
    const float* h0  = (const float*)d_in[1];
    const float* c0  = (const float*)d_in[2];
    const float* Wih = (const float*)d_in[3];
    const float* Whh = (const float*)d_in[4];
    const float* bih = (const float*)d_in[5];
    const float* bhh = (const float*)d_in[6];
    const float* Wfc = (const float*)d_in[7];
    const float* bfc = (const float*)d_in[8];
    float* out = (float*)d_out;

    // ws layout (needs ~67.6 MiB)
    char* w = (char*)d_ws;
    unsigned short* xb = (unsigned short*)(w);                  // 67,108,864 B
    unsigned short* Wp = (unsigned short*)(w + 67108864);       //  3,145,728 B
    float*          bp = (float*)(w + 70254592);                //      8,192 B
    unsigned short* hb = (unsigned short*)(w + 70262784);       //    524,288 B (2x h)
    int*           bar = (int*)(w + 70787072);                  //         16 B

    cvt_x  <<<32768, 256, 0, stream>>>(x, xb);
    prep_w <<<6144,  256, 0, stream>>>(Wih, Whh, bih, bhh, Wp, bp);
    init_hb<<<512,   256, 0, stream>>>(h0, hb, bar);

    void* args[6];
    args[0] = (void*)&xb;
    args[1] = (void*)&Wp;
    args[2] = (void*)&bp;
    args[3] = (void*)&c0;
    args[4] = (void*)&hb;
    args[5] = (void*)&bar;
    hipLaunchCooperativeKernel((const void*)lstm_kernel, dim3(256), dim3(256),
                               args, 0, stream);

    // T=512 even -> final h lives in parity-0 buffer
    fc_kernel<<<256, 128, 0, stream>>>(hb, Wfc, bfc, out);
}

// Round 2
// 3423.985 us; speedup vs baseline: 2.5694x; 2.5694x over previous
//
#include <hip/hip_runtime.h>

// Problem constants
#define B_ 256
#define T_ 512
#define F_ 256
#define H_ 512
#define E_ 128

#define BAR_STRIDE 64   // ints -> 256 B between per-cluster counters (no false sharing)

typedef __bf16 bf16x8 __attribute__((ext_vector_type(8)));
typedef float f32x4 __attribute__((ext_vector_type(4)));

__device__ __forceinline__ unsigned short f2bf(float f) {
    unsigned u = __float_as_uint(f);
    u += 0x7FFFu + ((u >> 16) & 1u);   // round-to-nearest-even
    return (unsigned short)(u >> 16);
}
__device__ __forceinline__ float bf2f(unsigned short s) {
    return __uint_as_float(((unsigned)s) << 16);
}
__device__ __forceinline__ float sigm(float x) {
    return 1.f / (1.f + __expf(-x));
}
__device__ __forceinline__ float tanh_f(float x) {
    return 2.f / (1.f + __expf(-2.f * x)) - 1.f;
}

// ---------------- prep kernels ----------------

// x fp32 -> bf16, 4 elements/thread
__global__ void cvt_x(const float* __restrict__ x, unsigned short* __restrict__ xb) {
    int i = blockIdx.x * 256 + threadIdx.x;       // 8,388,608 threads exactly
    float4 v = ((const float4*)x)[i];
    ushort4 o;
    o.x = f2bf(v.x); o.y = f2bf(v.y); o.z = f2bf(v.z); o.w = f2bf(v.w);
    ((ushort4*)xb)[i] = o;
}

// Build permuted combined weight matrix Wp[2048][768] (bf16) and bias bp[2048].
// New row nr = idx*32 + q*8 + jj  maps to old gate row  orow = q*512 + idx*8 + jj.
// k in [0,256) from W_ih, k in [256,768) from W_hh.
__global__ void prep_w(const float* __restrict__ Wih, const float* __restrict__ Whh,
                       const float* __restrict__ bih, const float* __restrict__ bhh,
                       unsigned short* __restrict__ Wp, float* __restrict__ bp) {
    int gid = blockIdx.x * 256 + threadIdx.x;     // 1,572,864 threads exactly
    int nr = gid / 768;
    int k  = gid - nr * 768;
    int idx = nr >> 5;
    int rem = nr & 31;
    int q  = rem >> 3;
    int jj = rem & 7;
    int orow = q * 512 + idx * 8 + jj;
    float v = (k < 256) ? Wih[orow * 256 + k] : Whh[orow * 512 + (k - 256)];
    Wp[gid] = f2bf(v);
    if (k == 0) bp[nr] = bih[orow] + bhh[orow];
}

// h0 fp32 -> bf16 into parity-0 h buffer; zero the (padded) barrier counters
__global__ void init_hb(const float* __restrict__ h0, unsigned short* __restrict__ hbuf,
                        int* __restrict__ bar) {
    int i = blockIdx.x * 256 + threadIdx.x;       // 131,072 threads exactly
    hbuf[i] = f2bf(h0[i]);
    if (blockIdx.x == 0 && threadIdx.x < 4 * BAR_STRIDE) bar[threadIdx.x] = 0;
}

// ---------------- persistent LSTM kernel (cooperative) ----------------
// grid = 256 blocks x 256 threads. Block bid: cluster = bid>>6 (64 batch rows),
// idx = bid&63 (8 h-cols -> 32 permuted gate rows, LDS-resident weights).
// Coherence protocol: h stores are 4B agent-scope relaxed atomics (write-through
// sc0 sc1), h loads are 8B agent-scope relaxed atomics (bypass stale L1/L2, served
// by Infinity Cache). NO fences anywhere -> no buffer_wbl2/buffer_inv per step.
__global__ void __launch_bounds__(256, 1) lstm_kernel(
        const unsigned short* __restrict__ xb,   // [B][T][F] bf16
        const unsigned short* __restrict__ Wp,   // [2048][768] bf16 (permuted)
        const float* __restrict__ bp,            // [2048] (permuted)
        const float* __restrict__ c0,            // [B][H] fp32
        unsigned short* __restrict__ hbuf,       // [2][B][H] bf16
        int* __restrict__ bar) {                 // padded monotonic counters

    __shared__ __align__(16) unsigned short Wl[32][776];  // 768 + 8 pad
    __shared__ float gl[64][33];                          // gate staging, +1 pad
    __shared__ float cl[64][8];                           // resident cell state

    const int tid = threadIdx.x;
    const int bid = blockIdx.x;
    const int cluster = bid >> 6;
    const int idx = bid & 63;
    const int m0 = cluster * 64;     // first batch row of cluster
    const int j0 = idx * 8;          // first h-col owned by this block
    const int gr0 = idx * 32;        // first permuted gate row

    // Stage weight slab (32 x 768 bf16) into LDS, once.
    {
        const ushort4* src = (const ushort4*)(Wp + (size_t)gr0 * 768);
        for (int v = tid; v < 32 * 192; v += 256) {
            int r = v / 192;
            int c = v - r * 192;
            *(ushort4*)&Wl[r][c * 4] = src[v];
        }
    }
    // Resident cell state init
    for (int p = tid; p < 512; p += 256) {
        int m = p >> 3, j = p & 7;
        cl[m][j] = c0[(size_t)(m0 + m) * H_ + j0 + j];
    }
    __syncthreads();

    const int lane = tid & 63;
    const int wave = tid >> 6;
    const int l16  = lane & 15;
    const int quad = lane >> 4;
    const int am   = m0 + wave * 16 + l16;   // this lane's A-row (global batch row)

    const float b0 = bp[gr0 + l16];          // bias for n-tile 0 (i,f)
    const float b1 = bp[gr0 + 16 + l16];     // bias for n-tile 1 (g,o)

    // elementwise-phase coordinates: thread handles 2 consecutive h cols
    const int em = tid >> 2;                 // 0..63  (local batch row)
    const int ej = (tid & 3) * 2;            // 0,2,4,6 (local h col pair)

    int* const mybar = bar + cluster * BAR_STRIDE;

    for (int t = 0; t < T_; ++t) {
        const int par = t & 1;
        const unsigned short* hsrc = hbuf + (size_t)par * (B_ * H_);
        unsigned short* hdst = hbuf + (size_t)(par ^ 1) * (B_ * H_);

        f32x4 acc0 = {b0, b0, b0, b0};
        f32x4 acc1 = {b1, b1, b1, b1};

        // ---- x-part (K = 0..256): independent of h -> runs before barrier wait
        {
            const unsigned short* xr =
                xb + (size_t)am * (T_ * F_) + (size_t)t * F_ + quad * 8;
            #pragma unroll
            for (int kk = 0; kk < 256; kk += 32) {
                bf16x8 a  = *(const bf16x8*)(xr + kk);
                bf16x8 w0 = *(const bf16x8*)&Wl[l16][kk + quad * 8];
                bf16x8 w1 = *(const bf16x8*)&Wl[16 + l16][kk + quad * 8];
                acc0 = __builtin_amdgcn_mfma_f32_16x16x32_bf16(a, w0, acc0, 0, 0, 0);
                acc1 = __builtin_amdgcn_mfma_f32_16x16x32_bf16(a, w1, acc1, 0, 0, 0);
            }
        }

        // ---- wait: h_t must be fully published (cnt >= 64*t)
        if (t > 0) {
            if (tid == 0) {
                const int target = t * 64;
                while (__hip_atomic_load(mybar, __ATOMIC_RELAXED,
                                         __HIP_MEMORY_SCOPE_AGENT) < target)
                    __builtin_amdgcn_s_sleep(1);
            }
            __syncthreads();
        }

        // ---- h-part (K = 256..768); loads bypass L1/L2 (agent-scope atomics)
        {
            const unsigned long long* hq = (const unsigned long long*)hsrc +
                (((size_t)am * H_ + quad * 8) >> 2);
            #pragma unroll
            for (int kk = 0; kk < 512; kk += 32) {
                union { unsigned long long q[2]; bf16x8 v; } ha;
                ha.q[0] = __hip_atomic_load(hq + (kk >> 2), __ATOMIC_RELAXED,
                                            __HIP_MEMORY_SCOPE_AGENT);
                ha.q[1] = __hip_atomic_load(hq + (kk >> 2) + 1, __ATOMIC_RELAXED,
                                            __HIP_MEMORY_SCOPE_AGENT);
                bf16x8 w0 = *(const bf16x8*)&Wl[l16][256 + kk + quad * 8];
                bf16x8 w1 = *(const bf16x8*)&Wl[16 + l16][256 + kk + quad * 8];
                acc0 = __builtin_amdgcn_mfma_f32_16x16x32_bf16(ha.v, w0, acc0, 0, 0, 0);
                acc1 = __builtin_amdgcn_mfma_f32_16x16x32_bf16(ha.v, w1, acc1, 0, 0, 0);
            }
        }

        // ---- epilogue: C-layout (col=lane&15, row=quad*4+reg) -> LDS
        #pragma unroll
        for (int r = 0; r < 4; ++r) {
            gl[wave * 16 + quad * 4 + r][l16]      = acc0[r];
            gl[wave * 16 + quad * 4 + r][16 + l16] = acc1[r];
        }
        __syncthreads();

        // elementwise gate math; local n layout is [i(8) f(8) g(8) o(8)].
        // Each thread computes 2 consecutive h cols and publishes them as one
        // packed 4B agent-scope (write-through) store.
        {
            float i0 = sigm(gl[em][ej]);
            float i1 = sigm(gl[em][ej + 1]);
            float f0 = sigm(gl[em][ej + 8]);
            float f1 = sigm(gl[em][ej + 9]);
            float g0 = tanh_f(gl[em][ej + 16]);
            float g1 = tanh_f(gl[em][ej + 17]);
            float o0 = sigm(gl[em][ej + 24]);
            float o1 = sigm(gl[em][ej + 25]);
            float c0v = f0 * cl[em][ej]     + i0 * g0;
            float c1v = f1 * cl[em][ej + 1] + i1 * g1;
            cl[em][ej]     = c0v;
            cl[em][ej + 1] = c1v;
            float h0v = o0 * tanh_f(c0v);
            float h1v = o1 * tanh_f(c1v);
            unsigned pack = (unsigned)f2bf(h0v) | ((unsigned)f2bf(h1v) << 16);
            unsigned* dst = (unsigned*)hdst +
                (((size_t)(m0 + em) * H_ + j0 + ej) >> 1);
            __hip_atomic_store(dst, pack, __ATOMIC_RELAXED,
                               __HIP_MEMORY_SCOPE_AGENT);
        }
        __syncthreads();   // all waves drained vmcnt(0) -> h globally visible
        if (tid == 0)
            __hip_atomic_fetch_add(mybar, 1, __ATOMIC_RELAXED,
                                   __HIP_MEMORY_SCOPE_AGENT);
    }
}

// ---------------- FC head ----------------
// out[m][e] = sigmoid(h_T[m] . W_fc[e] + b_fc[e]); grid = 256 (m), 128 threads (e)
__global__ void fc_kernel(const unsigned short* __restrict__ hT,
                          const float* __restrict__ Wfc,
                          const float* __restrict__ bfc,
                          float* __restrict__ out) {
    __shared__ float hs[512];
    int m = blockIdx.x;
    for (int k = threadIdx.x; k < 512; k += 128)
        hs[k] = bf2f(hT[(size_t)m * 512 + k]);
    __syncthreads();
    int e = threadIdx.x;
    const float4* w4 = (const float4*)(Wfc + (size_t)e * 512);
    float s = bfc[e];
    #pragma unroll 8
    for (int k4 = 0; k4 < 128; ++k4) {
        float4 w = w4[k4];
        s += hs[4 * k4] * w.x + hs[4 * k4 + 1] * w.y +
             hs[4 * k4 + 2] * w.z + hs[4 * k4 + 3] * w.w;
    }
    out[(size_t)m * 128 + e] = 1.f / (1.f + __expf(-s));
}

// ---------------- launch ----------------
extern "C" void kernel_launch(void* const* d_in, const int* in_sizes, int n_in,
                              void* d_out, int out_size, void* d_ws, size_t ws_size,
                              hipStream_t stream) {
    const float* x   = (const float*)d_in[0];
    const float* h0  = (const float*)d_in[1];
    const float* c0  = (const float*)d_in[2];
    const float* Wih = (const float*)d_in[3];
    const float* Whh = (const float*)d_in[4];
    const float* bih = (const float*)d_in[5];
    const float* bhh = (const float*)d_in[6];
    const float* Wfc = (const float*)d_in[7];
    const float* bfc = (const float*)d_in[8];
    float* out = (float*)d_out;

    // ws layout (needs ~67.6 MiB)
    char* w = (char*)d_ws;
    unsigned short* xb = (unsigned short*)(w);                  // 67,108,864 B
    unsigned short* Wp = (unsigned short*)(w + 67108864);       //  3,145,728 B
    float*          bp = (float*)(w + 70254592);                //      8,192 B
    unsigned short* hb = (unsigned short*)(w + 70262784);       //    524,288 B (2x h)
    int*           bar = (int*)(w + 70787072);                  //      1,024 B

    cvt_x  <<<32768, 256, 0, stream>>>(x, xb);
    prep_w <<<6144,  256, 0, stream>>>(Wih, Whh, bih, bhh, Wp, bp);
    init_hb<<<512,   256, 0, stream>>>(h0, hb, bar);

    void* args[6];
    args[0] = (void*)&xb;
    args[1] = (void*)&Wp;
    args[2] = (void*)&bp;
    args[3] = (void*)&c0;
    args[4] = (void*)&hb;
    args[5] = (void*)&bar;
    hipLaunchCooperativeKernel((const void*)lstm_kernel, dim3(256), dim3(256),
                               args, 0, stream);

    // T=512 even -> final h lives in parity-0 buffer
    fc_kernel<<<256, 128, 0, stream>>>(hb, Wfc, bfc, out);
}